// Round 17
// baseline (2578.020 us; speedup 1.0000x reference)
//
#include <hip/hip_runtime.h>

typedef _Float16 h2 __attribute__((ext_vector_type(2)));
typedef _Float16 h8 __attribute__((ext_vector_type(8)));

#define NB 128
#define NT 2048
#define NIN 32
#define NS 32
#define NM 8
#define NE 64
#define NH 128
#define NH3 384
#define RPW 32

__device__ __forceinline__ h2 mkh2(float a, float b) {
  h2 r; r[0] = (_Float16)a; r[1] = (_Float16)b; return r;
}

template <int I>
__device__ __forceinline__ h2 pick2(h8 v) {
  return __builtin_shufflevector(v, v, 2 * I, 2 * I + 1);
}

__device__ __forceinline__ float fdot2(h2 a, h2 b, float c) {
#if __has_builtin(__builtin_amdgcn_fdot2)
  return __builtin_amdgcn_fdot2(a, b, c, false);
#else
  return c + (float)a[0] * (float)b[0] + (float)a[1] * (float)b[1];
#endif
}

__device__ __forceinline__ float rcpf(float v) {
#if __has_builtin(__builtin_amdgcn_rcpf)
  return __builtin_amdgcn_rcpf(v);
#else
  return 1.0f / v;
#endif
}

__device__ __forceinline__ float sigmoid_f(float v) { return rcpf(1.0f + __expf(-v)); }
__device__ __forceinline__ float tanh_f(float v) { return 1.0f - 2.0f * rcpf(1.0f + __expf(2.0f * v)); }

__device__ __forceinline__ float f16bits_tof(unsigned short u) {
  _Float16 h;
  __builtin_memcpy(&h, &u, 2);
  return (float)h;
}

template <int CTRL>
__device__ __forceinline__ float dppadd(float v) {
  int t = __builtin_amdgcn_update_dpp(0, __float_as_int(v), CTRL, 0xF, 0xF, true);
  return v + __int_as_float(t);
}
__device__ __forceinline__ float wave_reduce63(float v) {
  v = dppadd<0x111>(v); v = dppadd<0x112>(v); v = dppadd<0x114>(v);
  v = dppadd<0x118>(v); v = dppadd<0x142>(v); v = dppadd<0x143>(v);
  return v;  // lane 63 holds the 64-lane sum
}
__device__ __forceinline__ float pairsum(float v) {
  int t = __builtin_amdgcn_update_dpp(0, __float_as_int(v), 0xB1, 0xF, 0xF, true);
  return v + __int_as_float(t);
}

__device__ __forceinline__ void lds_fence() {
  asm volatile("s_waitcnt lgkmcnt(0)" ::: "memory");
}

__device__ __forceinline__ void waitflag(int* f) {
  while (__hip_atomic_load(f, __ATOMIC_ACQUIRE, __HIP_MEMORY_SCOPE_AGENT) == 0)
    __builtin_amdgcn_s_sleep(2);
}

// ---------------------------------------------------------------------------
// Fused kernel. Blocks [0, NB): the r8 recurrent kernel (passed, byte-equal
// to r16's rnn role). Blocks [NB, NB + NB*CH/128): r11's PIPELINED pre body
// (passed in r11): register x-prefetch, RPW=32, 128 rows/block, 2 passes.
// Chunk-major remap: pre block pb -> batch pb%NB, 128-row chunk pb/NB; flag
// published (device-release) when the chunk's xpre/xh16 rows are complete.
// ---------------------------------------------------------------------------
__global__ __launch_bounds__(384, 1) void fused(
    const float* __restrict__ gx, const float* __restrict__ gy,
    const float* __restrict__ W_enc, const float* __restrict__ b_enc,
    const float* __restrict__ W_in, const float* __restrict__ W_rec,
    const float* __restrict__ b_s, const float* __restrict__ W_x,
    const float* __restrict__ W_h, const float* __restrict__ b_x,
    const float* __restrict__ b_h, const float* __restrict__ W_gate,
    const float* __restrict__ b_gate, _Float16* __restrict__ xpre,
    _Float16* __restrict__ xh16, float* __restrict__ out,
    float* __restrict__ state, int* __restrict__ flags, int t0, int CH) {
  const int tid = threadIdx.x;

  // ---- shared (role-exclusive usage) ----
  __shared__ __align__(16) _Float16 x16[4][NIN];
  __shared__ __align__(16) _Float16 encA[4][RPW][NE];
  __shared__ __align__(16) _Float16 h_sh[2][NH];
  __shared__ __align__(16) _Float16 xpre_sh[2][NH3];
  __shared__ __align__(16) float ns_sh[2][NS][NM];
  __shared__ __align__(16) float xd_sh[2][2 * NH];
  __shared__ __align__(16) float gp_sh[2][4][NM];
  __shared__ __align__(16) _Float16 kst_sh[NS];
  __shared__ float err_sh;
  __shared__ float y_lds[NT];

  if (blockIdx.x >= NB) {
    // ==================== PRE ROLE (r11 pipelined pre2 body) ====================
    const int pb = (int)blockIdx.x - NB;
    const int bb = pb % NB;   // batch
    const int cc = pb / NB;   // 128-row chunk within this batch
    if (tid < 256) {
      const int wv = tid >> 6, lane = tid & 63;
      h2 we[16];
#pragma unroll
      for (int i = 0; i < 16; ++i)
        we[i] = mkh2(W_enc[(2 * i) * NE + lane], W_enc[(2 * i + 1) * NE + lane]);
      const float be = b_enc[lane];
      const int tc0 = cc * 128 + wv * RPW;

      h2 wx3[96];
      float bx3[3];
#pragma unroll 1
      for (int pass = 0; pass < 2; ++pass) {
#pragma unroll
        for (int kk = 0; kk < 3; ++kk) {
          const int j = lane + 64 * (3 * pass + kk);
#pragma unroll
          for (int i = 0; i < 32; ++i)
            wx3[kk * 32 + i] = mkh2(W_x[(size_t)(2 * i) * NH3 + j],
                                    W_x[(size_t)(2 * i + 1) * NH3 + j]);
          bx3[kk] = b_x[j];
        }
        if (pass == 0) {
          float xreg = 0.f;
          if (lane < NIN) xreg = gx[((size_t)bb * NT + t0 + tc0) * NIN + lane];
#pragma unroll 1
          for (int r = 0; r < RPW; ++r) {
            const int tc = tc0 + r;
            const size_t g = (size_t)bb * CH + tc;
            if (lane < NIN) x16[wv][lane] = (_Float16)xreg;
            if (r + 1 < RPW && lane < NIN)
              xreg = gx[((size_t)bb * NT + t0 + tc + 1) * NIN + lane];
            lds_fence();
            if (lane < 16) {
              const unsigned v = *(const unsigned*)&x16[wv][2 * lane];
              ((unsigned*)xh16)[g * 16 + lane] = v;
            }
            const h8* xv8 = (const h8*)x16[wv];
            float a = be, c = 0.f;
#pragma unroll
            for (int i = 0; i < 4; ++i) {
              const h8 xv = xv8[i];
              a = fdot2(pick2<0>(xv), we[4 * i + 0], a);
              c = fdot2(pick2<1>(xv), we[4 * i + 1], c);
              a = fdot2(pick2<2>(xv), we[4 * i + 2], a);
              c = fdot2(pick2<3>(xv), we[4 * i + 3], c);
            }
            encA[wv][r][lane] = (_Float16)tanh_f(a + c);
            lds_fence();
            const h8* ev8 = (const h8*)encA[wv][r];
            h8 ev[8];
#pragma unroll
            for (int i = 0; i < 8; ++i) ev[i] = ev8[i];
#pragma unroll
            for (int kk = 0; kk < 3; ++kk) {
              float a0 = bx3[kk], c0 = 0.f;
#pragma unroll
              for (int i = 0; i < 8; ++i) {
                a0 = fdot2(pick2<0>(ev[i]), wx3[kk * 32 + 4 * i + 0], a0);
                c0 = fdot2(pick2<1>(ev[i]), wx3[kk * 32 + 4 * i + 1], c0);
                a0 = fdot2(pick2<2>(ev[i]), wx3[kk * 32 + 4 * i + 2], a0);
                c0 = fdot2(pick2<3>(ev[i]), wx3[kk * 32 + 4 * i + 3], c0);
              }
              xpre[g * NH3 + lane + 64 * kk] = (_Float16)(a0 + c0);
            }
          }
        } else {
          h8 ev[8], evn[8];
          {
            const h8* e8 = (const h8*)encA[wv][0];
#pragma unroll
            for (int i = 0; i < 8; ++i) ev[i] = e8[i];
          }
#pragma unroll 1
          for (int r = 0; r < RPW; ++r) {
            if (r + 1 < RPW) {
              const h8* e8 = (const h8*)encA[wv][r + 1];
#pragma unroll
              for (int i = 0; i < 8; ++i) evn[i] = e8[i];
            }
            const size_t g = (size_t)bb * CH + tc0 + r;
#pragma unroll
            for (int kk = 0; kk < 3; ++kk) {
              float a0 = bx3[kk], c0 = 0.f;
#pragma unroll
              for (int i = 0; i < 8; ++i) {
                a0 = fdot2(pick2<0>(ev[i]), wx3[kk * 32 + 4 * i + 0], a0);
                c0 = fdot2(pick2<1>(ev[i]), wx3[kk * 32 + 4 * i + 1], c0);
                a0 = fdot2(pick2<2>(ev[i]), wx3[kk * 32 + 4 * i + 2], a0);
                c0 = fdot2(pick2<3>(ev[i]), wx3[kk * 32 + 4 * i + 3], c0);
              }
              xpre[g * NH3 + lane + 64 * (3 + kk)] = (_Float16)(a0 + c0);
            }
#pragma unroll
            for (int i = 0; i < 8; ++i) ev[i] = evn[i];
          }
        }
      }
    }
    // drain this thread's global stores, then join all waves
    asm volatile("s_waitcnt vmcnt(0)" ::: "memory");
    __syncthreads();
    if (tid == 0) {
      __threadfence();  // device-scope release for the xpre/xh16 stores
      __hip_atomic_store(&flags[pb], 1, __ATOMIC_RELEASE,
                         __HIP_MEMORY_SCOPE_AGENT);
    }
    return;
  }

  // ==================== RNN ROLE (r8 body + flag waits; 128-row flags) ====
  const int b = blockIdx.x;
  const int wv = tid >> 6;
  const int lane = tid & 63;

  float* st = state + b * (NH + NS + 1);

  h2 wbig[96];        // G: W_h 3 half-cols ; X: W_in 4 cols
  h2 wrec[16];        // G: W_rec col
  float wg[8];
  float bh[3], wxe[3];
  float bs4[4];
  float bg[8];
  float h_prev = 0.f;
  unsigned xpq[12];   // X: xpre rows tc4..tc4+3 (3 dwords each)
  h8 xr0[4], xr1[4], xr2[4], xr3[4];  // X: x rows
  int readyf = -1;

  const int gl = tid - 128;          // G: 0..255
  const int j = gl >> 1;             // G column
  const int half = gl & 1;

  // y preload (all waves) — one-time vmem, drained at the init barrier
  for (int i = tid; i < CH; i += 384) y_lds[i] = gy[(size_t)b * NT + t0 + i];

  if (wv >= 2) {
#pragma unroll
    for (int g = 0; g < 3; ++g) {
      const int jc = j + 128 * g;
#pragma unroll
      for (int i = 0; i < 32; ++i)
        wbig[g * 32 + i] = mkh2(W_h[(size_t)(64 * half + 2 * i) * NH3 + jc],
                                W_h[(size_t)(64 * half + 2 * i + 1) * NH3 + jc]);
      bh[g] = b_h[jc];
      wxe[g] = W_x[(size_t)NE * NH3 + jc];
    }
#pragma unroll
    for (int m = 0; m < 8; ++m) wg[m] = half ? 0.f : W_gate[j * NM + m];
    {
      const int m0 = gl >> 5, d0 = gl & 31;
#pragma unroll
      for (int i = 0; i < 16; ++i)
        wrec[i] = mkh2(W_rec[m0 * 1024 + (2 * i) * 32 + d0],
                       W_rec[m0 * 1024 + (2 * i + 1) * 32 + d0]);
    }
    h_prev = t0 ? st[j] : 0.f;
    if (!half) h_sh[1][j] = (_Float16)h_prev;
  } else if (wv == 1) {
#pragma unroll
    for (int k = 0; k < 4; ++k) {
      const int o = lane + 64 * k, m = o >> 5, d = o & 31;
#pragma unroll
      for (int i = 0; i < 16; ++i)
        wbig[k * 16 + i] = mkh2(W_in[m * 1024 + (2 * i) * 32 + d],
                                W_in[m * 1024 + (2 * i + 1) * 32 + d]);
      bs4[k] = b_s[o];
    }
    // wait for this batch's chunk 0 (rows 0..127) before reading xh16 rows 0..4
    waitflag(&flags[b]);
    readyf = b;
    // prologue: xd for step 0 from x row 0
    {
      const h8* x0 = (const h8*)(xh16 + (size_t)(b * CH) * NIN);
#pragma unroll
      for (int i = 0; i < 4; ++i) xr0[i] = x0[i];
#pragma unroll
      for (int k = 0; k < 4; ++k) {
        float s = bs4[k];
#pragma unroll
        for (int i = 0; i < 4; ++i) {
          s = fdot2(pick2<0>(xr0[i]), wbig[k * 16 + 4 * i + 0], s);
          s = fdot2(pick2<1>(xr0[i]), wbig[k * 16 + 4 * i + 1], s);
          s = fdot2(pick2<2>(xr0[i]), wbig[k * 16 + 4 * i + 2], s);
          s = fdot2(pick2<3>(xr0[i]), wbig[k * 16 + 4 * i + 3], s);
        }
        xd_sh[1][lane + 64 * k] = s;
      }
    }
  } else { // S
#pragma unroll
    for (int m = 0; m < 8; ++m) bg[m] = b_gate[m];
    if (lane < NS) kst_sh[lane] = t0 ? (_Float16)st[NH + lane] : (_Float16)0.f;
    if (lane == 0) err_sh = t0 ? st[NH + NS] : 0.f;
  }
  __syncthreads();

  float hz = 0.f, hr = 0.f, hn = 0.f;

#define STEPK(K, XRK)                                                          \
  {                                                                            \
    const int tc = tc4 + (K);                                                  \
    const int q = (K) & 1, qp = q ^ 1;                                         \
    /* ---------------- part A ---------------- */                             \
    if (wv >= 2) {                                                             \
      const h8* hv8 = (const h8*)&h_sh[qp][64 * half];                         \
      float a0 = 0.f, c0 = 0.f, a1 = 0.f, c1 = 0.f, a2 = 0.f, c2 = 0.f;        \
      _Pragma("unroll")                                                        \
      for (int i = 0; i < 8; ++i) {                                            \
        const h8 hv = hv8[i];                                                  \
        a0 = fdot2(pick2<0>(hv), wbig[4 * i + 0], a0);                         \
        c0 = fdot2(pick2<1>(hv), wbig[4 * i + 1], c0);                         \
        a0 = fdot2(pick2<2>(hv), wbig[4 * i + 2], a0);                         \
        c0 = fdot2(pick2<3>(hv), wbig[4 * i + 3], c0);                         \
        a1 = fdot2(pick2<0>(hv), wbig[32 + 4 * i + 0], a1);                    \
        c1 = fdot2(pick2<1>(hv), wbig[32 + 4 * i + 1], c1);                    \
        a1 = fdot2(pick2<2>(hv), wbig[32 + 4 * i + 2], a1);                    \
        c1 = fdot2(pick2<3>(hv), wbig[32 + 4 * i + 3], c1);                    \
        a2 = fdot2(pick2<0>(hv), wbig[64 + 4 * i + 0], a2);                    \
        c2 = fdot2(pick2<1>(hv), wbig[64 + 4 * i + 1], c2);                    \
        a2 = fdot2(pick2<2>(hv), wbig[64 + 4 * i + 2], a2);                    \
        c2 = fdot2(pick2<3>(hv), wbig[64 + 4 * i + 3], c2);                    \
      }                                                                        \
      hz = pairsum(a0 + c0) + bh[0];                                           \
      hr = pairsum(a1 + c1) + bh[1];                                           \
      hn = pairsum(a2 + c2) + bh[2];                                           \
    } else if (wv == 0) {                                                      \
      if (tc > 0) {                                                            \
        const int u = lane & 31;                                               \
        const float4* nsv = (const float4*)&ns_sh[qp][u][0];                   \
        const float4 n0 = nsv[0], n1 = nsv[1];                                 \
        const float4* g4 = (const float4*)&gp_sh[qp][0][0];                    \
        float4 A = g4[0], Bv = g4[1];                                          \
        A.x += g4[2].x + g4[4].x + g4[6].x; A.y += g4[2].y + g4[4].y + g4[6].y;\
        A.z += g4[2].z + g4[4].z + g4[6].z; A.w += g4[2].w + g4[4].w + g4[6].w;\
        Bv.x += g4[3].x + g4[5].x + g4[7].x; Bv.y += g4[3].y + g4[5].y + g4[7].y;\
        Bv.z += g4[3].z + g4[5].z + g4[7].z; Bv.w += g4[3].w + g4[5].w + g4[7].w;\
        float l[8] = {A.x + bg[0], A.y + bg[1], A.z + bg[2], A.w + bg[3],      \
                      Bv.x + bg[4], Bv.y + bg[5], Bv.z + bg[6], Bv.w + bg[7]}; \
        float mx = fmaxf(fmaxf(fmaxf(l[0], l[1]), fmaxf(l[2], l[3])),          \
                         fmaxf(fmaxf(l[4], l[5]), fmaxf(l[6], l[7])));         \
        float e[8], s = 0.f;                                                   \
        _Pragma("unroll")                                                      \
        for (int m = 0; m < 8; ++m) { e[m] = __expf(l[m] - mx); s += e[m]; }   \
        float ks = e[0] * n0.x + e[1] * n0.y + e[2] * n0.z + e[3] * n0.w +     \
                   e[4] * n1.x + e[5] * n1.y + e[6] * n1.z + e[7] * n1.w;      \
        ks *= rcpf(s);                                                         \
        if (lane < NS) kst_sh[u] = (_Float16)ks;                               \
        if (lane == 31) {                                                      \
          out[(size_t)b * NT + t0 + tc - 1] = ks;                              \
          err_sh = ks - y_lds[tc - 1];                                         \
        }                                                                      \
      }                                                                        \
    } else { /* X: wait flag, batch issue at K==0, stage row tc */             \
      if ((K) == 0) {                                                          \
        const int needf = (min(tc4 + 8, CH - 1) >> 7) * NB + b;                \
        if (needf > readyf) { waitflag(&flags[needf]); readyf = needf; }       \
        const unsigned* xpg = (const unsigned*)xpre;                           \
        _Pragma("unroll")                                                      \
        for (int k = 0; k < 4; ++k) {                                          \
          const size_t rr = (size_t)(b * CH + tc4 + k) * 192;                  \
          xpq[3 * k + 0] = xpg[rr + lane];                                     \
          xpq[3 * k + 1] = xpg[rr + lane + 64];                                \
          xpq[3 * k + 2] = xpg[rr + lane + 128];                               \
        }                                                                      \
        const h8* xg0 = (const h8*)(xh16 + (size_t)(b * CH + min(tc4 + 1, CH - 1)) * NIN); \
        const h8* xg1 = (const h8*)(xh16 + (size_t)(b * CH + min(tc4 + 2, CH - 1)) * NIN); \
        const h8* xg2 = (const h8*)(xh16 + (size_t)(b * CH + min(tc4 + 3, CH - 1)) * NIN); \
        const h8* xg3 = (const h8*)(xh16 + (size_t)(b * CH + min(tc4 + 4, CH - 1)) * NIN); \
        _Pragma("unroll")                                                      \
        for (int i = 0; i < 4; ++i) {                                          \
          xr0[i] = xg0[i]; xr1[i] = xg1[i]; xr2[i] = xg2[i]; xr3[i] = xg3[i];  \
        }                                                                      \
      }                                                                        \
      unsigned* xps = (unsigned*)&xpre_sh[q][0];                               \
      xps[lane] = xpq[3 * (K) + 0];                                            \
      xps[lane + 64] = xpq[3 * (K) + 1];                                       \
      xps[lane + 128] = xpq[3 * (K) + 2];                                      \
    }                                                                          \
    __syncthreads();                                                           \
    /* ---------------- part B ---------------- */                             \
    if (wv >= 2) {                                                             \
      const float err = err_sh;                                                \
      const float xz = (float)xpre_sh[q][j] + err * wxe[0];                    \
      const float xr = (float)xpre_sh[q][j + 128] + err * wxe[1];              \
      const float xn = (float)xpre_sh[q][j + 256] + err * wxe[2];              \
      const float z = sigmoid_f(hz + xz);                                      \
      const float r = sigmoid_f(hr + xr);                                      \
      const float n = tanh_f(xn + r * hn);                                     \
      const float hnew = (1.f - z) * n + z * h_prev;                           \
      h_prev = hnew;                                                           \
      if (!half) h_sh[q][j] = (_Float16)hnew;                                  \
      float p[8];                                                              \
      _Pragma("unroll")                                                        \
      for (int m = 0; m < 8; ++m) p[m] = wave_reduce63(hnew * wg[m]);          \
      if (lane == 63) {                                                        \
        *(float4*)&gp_sh[q][wv - 2][0] = make_float4(p[0], p[1], p[2], p[3]);  \
        *(float4*)&gp_sh[q][wv - 2][4] = make_float4(p[4], p[5], p[6], p[7]);  \
      }                                                                        \
      const h8* kv8 = (const h8*)kst_sh;                                       \
      float s = xd_sh[qp][gl];                                                 \
      _Pragma("unroll")                                                        \
      for (int i = 0; i < 4; ++i) {                                            \
        const h8 kv = kv8[i];                                                  \
        s = fdot2(pick2<0>(kv), wrec[4 * i + 0], s);                           \
        s = fdot2(pick2<1>(kv), wrec[4 * i + 1], s);                           \
        s = fdot2(pick2<2>(kv), wrec[4 * i + 2], s);                           \
        s = fdot2(pick2<3>(kv), wrec[4 * i + 3], s);                           \
      }                                                                        \
      ns_sh[q][gl & 31][gl >> 5] = tanh_f(s);                                  \
    } else if (wv == 1) {                                                      \
      if (tc + 1 < CH) {                                                       \
        _Pragma("unroll")                                                      \
        for (int k = 0; k < 4; ++k) {                                          \
          float s = bs4[k];                                                    \
          _Pragma("unroll")                                                    \
          for (int i = 0; i < 4; ++i) {                                        \
            s = fdot2(pick2<0>(XRK[i]), wbig[k * 16 + 4 * i + 0], s);          \
            s = fdot2(pick2<1>(XRK[i]), wbig[k * 16 + 4 * i + 1], s);          \
            s = fdot2(pick2<2>(XRK[i]), wbig[k * 16 + 4 * i + 2], s);          \
            s = fdot2(pick2<3>(XRK[i]), wbig[k * 16 + 4 * i + 3], s);          \
          }                                                                    \
          xd_sh[q][lane + 64 * k] = s;                                         \
        }                                                                      \
      }                                                                        \
    }                                                                          \
    __syncthreads();                                                           \
  }

  for (int tc4 = 0; tc4 < CH; tc4 += 4) {
    STEPK(0, xr0)
    STEPK(1, xr1)
    STEPK(2, xr2)
    STEPK(3, xr3)
  }
#undef STEPK

  // ---- epilogue: softmax for the chunk's last step + state save ----
  if (wv == 0) {
    const int qf = (CH - 1) & 1;
    const int u = lane & 31;
    const float4* nsv = (const float4*)&ns_sh[qf][u][0];
    const float4 n0 = nsv[0], n1 = nsv[1];
    const float4* g4 = (const float4*)&gp_sh[qf][0][0];
    float4 A = g4[0], Bv = g4[1];
    A.x += g4[2].x + g4[4].x + g4[6].x; A.y += g4[2].y + g4[4].y + g4[6].y;
    A.z += g4[2].z + g4[4].z + g4[6].z; A.w += g4[2].w + g4[4].w + g4[6].w;
    Bv.x += g4[3].x + g4[5].x + g4[7].x; Bv.y += g4[3].y + g4[5].y + g4[7].y;
    Bv.z += g4[3].z + g4[5].z + g4[7].z; Bv.w += g4[3].w + g4[5].w + g4[7].w;
    float l[8] = {A.x + bg[0], A.y + bg[1], A.z + bg[2], A.w + bg[3],
                  Bv.x + bg[4], Bv.y + bg[5], Bv.z + bg[6], Bv.w + bg[7]};
    float mx = fmaxf(fmaxf(fmaxf(l[0], l[1]), fmaxf(l[2], l[3])),
                     fmaxf(fmaxf(l[4], l[5]), fmaxf(l[6], l[7])));
    float e[8], s = 0.f;
#pragma unroll
    for (int m = 0; m < 8; ++m) { e[m] = __expf(l[m] - mx); s += e[m]; }
    float ks = e[0] * n0.x + e[1] * n0.y + e[2] * n0.z + e[3] * n0.w +
               e[4] * n1.x + e[5] * n1.y + e[6] * n1.z + e[7] * n1.w;
    ks *= rcpf(s);
    if (lane < NS) st[NH + u] = ks;
    if (lane == 31) {
      out[(size_t)b * NT + t0 + CH - 1] = ks;
      st[NH + NS] = ks - y_lds[CH - 1];
    }
  }
  if (wv >= 2 && !half) st[j] = h_prev;
}

extern "C" void kernel_launch(void* const* d_in, const int* in_sizes, int n_in,
                              void* d_out, int out_size, void* d_ws, size_t ws_size,
                              hipStream_t stream) {
  const float* x = (const float*)d_in[0];
  const float* y = (const float*)d_in[1];
  const float* W_enc = (const float*)d_in[2];
  const float* b_enc = (const float*)d_in[3];
  const float* W_in = (const float*)d_in[4];
  const float* W_rec = (const float*)d_in[5];
  const float* b_s = (const float*)d_in[6];
  const float* W_x = (const float*)d_in[7];
  const float* W_h = (const float*)d_in[8];
  const float* b_x = (const float*)d_in[9];
  const float* b_h = (const float*)d_in[10];
  const float* W_gate = (const float*)d_in[11];
  const float* b_gate = (const float*)d_in[12];
  float* out = (float*)d_out;

  const size_t stateB = (size_t)NB * (NH + NS + 1) * sizeof(float);
  int CH = NT;
  while (CH > 128) {
    const size_t need = (size_t)NB * CH * NH3 * 2 + (size_t)NB * CH * NIN * 2 +
                        stateB + (size_t)(NB * CH / 128) * sizeof(int);
    if (need <= ws_size) break;
    CH >>= 1;
  }
  const int npre = NB * CH / 128;

  _Float16* xpre = (_Float16*)d_ws;
  _Float16* xh16 = (_Float16*)((char*)d_ws + (size_t)NB * CH * NH3 * 2);
  float* state = (float*)((char*)d_ws + (size_t)NB * CH * NH3 * 2 +
                          (size_t)NB * CH * NIN * 2);
  int* flags = (int*)((char*)state + stateB);

  for (int t0 = 0; t0 < NT; t0 += CH) {
    (void)hipMemsetAsync(flags, 0, (size_t)npre * sizeof(int), stream);
    fused<<<dim3(NB + npre), dim3(384), 0, stream>>>(
        x, y, W_enc, b_enc, W_in, W_rec, b_s, W_x, W_h, b_x, b_h, W_gate,
        b_gate, xpre, xh16, out, state, flags, t0, CH);
  }
}

// Round 18
// 2551.252 us; speedup vs baseline: 1.0105x; 1.0105x over previous
//
#include <hip/hip_runtime.h>

typedef _Float16 h2 __attribute__((ext_vector_type(2)));
typedef _Float16 h8 __attribute__((ext_vector_type(8)));

#define NB 128
#define NT 2048
#define NIN 32
#define NS 32
#define NM 8
#define NE 64
#define NH 128
#define NH3 384
#define RPW 16

__device__ __forceinline__ h2 mkh2(float a, float b) {
  h2 r; r[0] = (_Float16)a; r[1] = (_Float16)b; return r;
}

template <int I>
__device__ __forceinline__ h2 pick2(h8 v) {
  return __builtin_shufflevector(v, v, 2 * I, 2 * I + 1);
}

__device__ __forceinline__ float fdot2(h2 a, h2 b, float c) {
#if __has_builtin(__builtin_amdgcn_fdot2)
  return __builtin_amdgcn_fdot2(a, b, c, false);
#else
  return c + (float)a[0] * (float)b[0] + (float)a[1] * (float)b[1];
#endif
}

__device__ __forceinline__ float rcpf(float v) {
#if __has_builtin(__builtin_amdgcn_rcpf)
  return __builtin_amdgcn_rcpf(v);
#else
  return 1.0f / v;
#endif
}

__device__ __forceinline__ float sigmoid_f(float v) { return rcpf(1.0f + __expf(-v)); }
__device__ __forceinline__ float tanh_f(float v) { return 1.0f - 2.0f * rcpf(1.0f + __expf(2.0f * v)); }

__device__ __forceinline__ float f16bits_tof(unsigned short u) {
  _Float16 h;
  __builtin_memcpy(&h, &u, 2);
  return (float)h;
}

template <int CTRL>
__device__ __forceinline__ float dppadd(float v) {
  int t = __builtin_amdgcn_update_dpp(0, __float_as_int(v), CTRL, 0xF, 0xF, true);
  return v + __int_as_float(t);
}
__device__ __forceinline__ float wave_reduce63(float v) {
  v = dppadd<0x111>(v); v = dppadd<0x112>(v); v = dppadd<0x114>(v);
  v = dppadd<0x118>(v); v = dppadd<0x142>(v); v = dppadd<0x143>(v);
  return v;  // lane 63 holds the 64-lane sum
}
__device__ __forceinline__ float pairsum(float v) {
  int t = __builtin_amdgcn_update_dpp(0, __float_as_int(v), 0xB1, 0xF, 0xF, true);
  return v + __int_as_float(t);
}

__device__ __forceinline__ void lds_fence() {
  asm volatile("s_waitcnt lgkmcnt(0)" ::: "memory");
}

__device__ __forceinline__ void waitflag(int* f) {
  while (__hip_atomic_load(f, __ATOMIC_ACQUIRE, __HIP_MEMORY_SCOPE_AGENT) == 0)
    __builtin_amdgcn_s_sleep(2);
}

// ---------------------------------------------------------------------------
// Fused kernel (r16, best so far) + priority split: rnn waves at s_setprio(1)
// for the whole kernel, pre waves at default 0. Blocks [0, NB): r8 recurrent
// body. Blocks [NB, NB + NB*CH/64): r8 pre body, chunk-major remap, 64-row
// ready flags (device-release / acquire).
// ---------------------------------------------------------------------------
__global__ __launch_bounds__(384, 1) void fused(
    const float* __restrict__ gx, const float* __restrict__ gy,
    const float* __restrict__ W_enc, const float* __restrict__ b_enc,
    const float* __restrict__ W_in, const float* __restrict__ W_rec,
    const float* __restrict__ b_s, const float* __restrict__ W_x,
    const float* __restrict__ W_h, const float* __restrict__ b_x,
    const float* __restrict__ b_h, const float* __restrict__ W_gate,
    const float* __restrict__ b_gate, _Float16* __restrict__ xpre,
    _Float16* __restrict__ xh16, float* __restrict__ out,
    float* __restrict__ state, int* __restrict__ flags, int t0, int CH) {
  const int tid = threadIdx.x;

  // ---- shared (role-exclusive usage) ----
  __shared__ __align__(16) _Float16 x16[4][NIN];
  __shared__ __align__(16) _Float16 encA[4][RPW][NE];
  __shared__ __align__(16) _Float16 h_sh[2][NH];
  __shared__ __align__(16) _Float16 xpre_sh[2][NH3];
  __shared__ __align__(16) float ns_sh[2][NS][NM];
  __shared__ __align__(16) float xd_sh[2][2 * NH];
  __shared__ __align__(16) float gp_sh[2][4][NM];
  __shared__ __align__(16) _Float16 kst_sh[NS];
  __shared__ float err_sh;
  __shared__ float y_lds[NT];

  if (blockIdx.x >= NB) {
    // ==================== PRE ROLE (r8 pre2 body, prio 0) ====================
    const int pb = (int)blockIdx.x - NB;
    const int bb = pb % NB;   // batch
    const int cc = pb / NB;   // 64-row chunk within this batch's CH rows
    if (tid < 256) {
      const int wv = tid >> 6, lane = tid & 63;
      h2 we[16];
#pragma unroll
      for (int i = 0; i < 16; ++i)
        we[i] = mkh2(W_enc[(2 * i) * NE + lane], W_enc[(2 * i + 1) * NE + lane]);
      const float be = b_enc[lane];
      const int tc0 = cc * 64 + wv * RPW;

      h2 wx3[96];
#pragma unroll 1
      for (int pass = 0; pass < 2; ++pass) {
#pragma unroll
        for (int kk = 0; kk < 3; ++kk) {
          const int j = lane + 64 * (3 * pass + kk);
#pragma unroll
          for (int i = 0; i < 32; ++i)
            wx3[kk * 32 + i] = mkh2(W_x[(size_t)(2 * i) * NH3 + j],
                                    W_x[(size_t)(2 * i + 1) * NH3 + j]);
        }
#pragma unroll 1
        for (int r = 0; r < RPW; ++r) {
          const int tc = tc0 + r;
          const size_t g = (size_t)bb * CH + tc;
          if (pass == 0) {
            const float* xr = gx + ((size_t)bb * NT + t0 + tc) * NIN;
            if (lane < NIN) x16[wv][lane] = (_Float16)xr[lane];
            lds_fence();
            if (lane < 16) {
              const unsigned v = *(const unsigned*)&x16[wv][2 * lane];
              ((unsigned*)xh16)[g * 16 + lane] = v;
            }
            const h8* xv8 = (const h8*)x16[wv];
            float a = be;
#pragma unroll
            for (int i = 0; i < 4; ++i) {
              const h8 xv = xv8[i];
              a = fdot2(pick2<0>(xv), we[4 * i + 0], a);
              a = fdot2(pick2<1>(xv), we[4 * i + 1], a);
              a = fdot2(pick2<2>(xv), we[4 * i + 2], a);
              a = fdot2(pick2<3>(xv), we[4 * i + 3], a);
            }
            encA[wv][r][lane] = (_Float16)tanh_f(a);
            lds_fence();
          }
          // FULL 64-element dot (r8 fix)
          const h8* ev8 = (const h8*)encA[wv][r];
          h8 ev[8];
#pragma unroll
          for (int i = 0; i < 8; ++i) ev[i] = ev8[i];
#pragma unroll
          for (int kk = 0; kk < 3; ++kk) {
            const int j = lane + 64 * (3 * pass + kk);
            float a = b_x[j], c = 0.f;
#pragma unroll
            for (int i = 0; i < 8; ++i) {
              a = fdot2(pick2<0>(ev[i]), wx3[kk * 32 + 4 * i + 0], a);
              c = fdot2(pick2<1>(ev[i]), wx3[kk * 32 + 4 * i + 1], c);
              a = fdot2(pick2<2>(ev[i]), wx3[kk * 32 + 4 * i + 2], a);
              c = fdot2(pick2<3>(ev[i]), wx3[kk * 32 + 4 * i + 3], c);
            }
            xpre[g * NH3 + j] = (_Float16)(a + c);
          }
        }
      }
    }
    // drain this thread's global stores, then join all waves
    asm volatile("s_waitcnt vmcnt(0)" ::: "memory");
    __syncthreads();
    if (tid == 0) {
      __threadfence();  // device-scope release for the xpre/xh16 stores
      __hip_atomic_store(&flags[pb], 1, __ATOMIC_RELEASE,
                         __HIP_MEMORY_SCOPE_AGENT);
    }
    return;
  }

  // ==================== RNN ROLE (r8 body, prio 1, flag waits) ====================
  __builtin_amdgcn_s_setprio(1);  // latency-critical: win CU arbitration vs pre waves
  const int b = blockIdx.x;
  const int wv = tid >> 6;
  const int lane = tid & 63;

  float* st = state + b * (NH + NS + 1);

  h2 wbig[96];        // G: W_h 3 half-cols ; X: W_in 4 cols
  h2 wrec[16];        // G: W_rec col
  float wg[8];
  float bh[3], wxe[3];
  float bs4[4];
  float bg[8];
  float h_prev = 0.f;
  unsigned xpq[12];   // X: xpre rows tc4..tc4+3 (3 dwords each)
  h8 xr0[4], xr1[4], xr2[4], xr3[4];  // X: x rows
  int readyf = -1;

  const int gl = tid - 128;          // G: 0..255
  const int j = gl >> 1;             // G column
  const int half = gl & 1;

  // y preload (all waves) — one-time vmem, drained at the init barrier
  for (int i = tid; i < CH; i += 384) y_lds[i] = gy[(size_t)b * NT + t0 + i];

  if (wv >= 2) {
#pragma unroll
    for (int g = 0; g < 3; ++g) {
      const int jc = j + 128 * g;
#pragma unroll
      for (int i = 0; i < 32; ++i)
        wbig[g * 32 + i] = mkh2(W_h[(size_t)(64 * half + 2 * i) * NH3 + jc],
                                W_h[(size_t)(64 * half + 2 * i + 1) * NH3 + jc]);
      bh[g] = b_h[jc];
      wxe[g] = W_x[(size_t)NE * NH3 + jc];
    }
#pragma unroll
    for (int m = 0; m < 8; ++m) wg[m] = half ? 0.f : W_gate[j * NM + m];
    {
      const int m0 = gl >> 5, d0 = gl & 31;
#pragma unroll
      for (int i = 0; i < 16; ++i)
        wrec[i] = mkh2(W_rec[m0 * 1024 + (2 * i) * 32 + d0],
                       W_rec[m0 * 1024 + (2 * i + 1) * 32 + d0]);
    }
    h_prev = t0 ? st[j] : 0.f;
    if (!half) h_sh[1][j] = (_Float16)h_prev;
  } else if (wv == 1) {
#pragma unroll
    for (int k = 0; k < 4; ++k) {
      const int o = lane + 64 * k, m = o >> 5, d = o & 31;
#pragma unroll
      for (int i = 0; i < 16; ++i)
        wbig[k * 16 + i] = mkh2(W_in[m * 1024 + (2 * i) * 32 + d],
                                W_in[m * 1024 + (2 * i + 1) * 32 + d]);
      bs4[k] = b_s[o];
    }
    // wait for this batch's chunk 0 (rows 0..63) before reading xh16 rows 0..4
    waitflag(&flags[b]);
    readyf = b;
    // prologue: xd for step 0 from x row 0
    {
      const h8* x0 = (const h8*)(xh16 + (size_t)(b * CH) * NIN);
#pragma unroll
      for (int i = 0; i < 4; ++i) xr0[i] = x0[i];
#pragma unroll
      for (int k = 0; k < 4; ++k) {
        float s = bs4[k];
#pragma unroll
        for (int i = 0; i < 4; ++i) {
          s = fdot2(pick2<0>(xr0[i]), wbig[k * 16 + 4 * i + 0], s);
          s = fdot2(pick2<1>(xr0[i]), wbig[k * 16 + 4 * i + 1], s);
          s = fdot2(pick2<2>(xr0[i]), wbig[k * 16 + 4 * i + 2], s);
          s = fdot2(pick2<3>(xr0[i]), wbig[k * 16 + 4 * i + 3], s);
        }
        xd_sh[1][lane + 64 * k] = s;
      }
    }
  } else { // S
#pragma unroll
    for (int m = 0; m < 8; ++m) bg[m] = b_gate[m];
    if (lane < NS) kst_sh[lane] = t0 ? (_Float16)st[NH + lane] : (_Float16)0.f;
    if (lane == 0) err_sh = t0 ? st[NH + NS] : 0.f;
  }
  __syncthreads();

  float hz = 0.f, hr = 0.f, hn = 0.f;

#define STEPK(K, XRK)                                                          \
  {                                                                            \
    const int tc = tc4 + (K);                                                  \
    const int q = (K) & 1, qp = q ^ 1;                                         \
    /* ---------------- part A ---------------- */                             \
    if (wv >= 2) {                                                             \
      const h8* hv8 = (const h8*)&h_sh[qp][64 * half];                         \
      float a0 = 0.f, c0 = 0.f, a1 = 0.f, c1 = 0.f, a2 = 0.f, c2 = 0.f;        \
      _Pragma("unroll")                                                        \
      for (int i = 0; i < 8; ++i) {                                            \
        const h8 hv = hv8[i];                                                  \
        a0 = fdot2(pick2<0>(hv), wbig[4 * i + 0], a0);                         \
        c0 = fdot2(pick2<1>(hv), wbig[4 * i + 1], c0);                         \
        a0 = fdot2(pick2<2>(hv), wbig[4 * i + 2], a0);                         \
        c0 = fdot2(pick2<3>(hv), wbig[4 * i + 3], c0);                         \
        a1 = fdot2(pick2<0>(hv), wbig[32 + 4 * i + 0], a1);                    \
        c1 = fdot2(pick2<1>(hv), wbig[32 + 4 * i + 1], c1);                    \
        a1 = fdot2(pick2<2>(hv), wbig[32 + 4 * i + 2], a1);                    \
        c1 = fdot2(pick2<3>(hv), wbig[32 + 4 * i + 3], c1);                    \
        a2 = fdot2(pick2<0>(hv), wbig[64 + 4 * i + 0], a2);                    \
        c2 = fdot2(pick2<1>(hv), wbig[64 + 4 * i + 1], c2);                    \
        a2 = fdot2(pick2<2>(hv), wbig[64 + 4 * i + 2], a2);                    \
        c2 = fdot2(pick2<3>(hv), wbig[64 + 4 * i + 3], c2);                    \
      }                                                                        \
      hz = pairsum(a0 + c0) + bh[0];                                           \
      hr = pairsum(a1 + c1) + bh[1];                                           \
      hn = pairsum(a2 + c2) + bh[2];                                           \
    } else if (wv == 0) {                                                      \
      if (tc > 0) {                                                            \
        const int u = lane & 31;                                               \
        const float4* nsv = (const float4*)&ns_sh[qp][u][0];                   \
        const float4 n0 = nsv[0], n1 = nsv[1];                                 \
        const float4* g4 = (const float4*)&gp_sh[qp][0][0];                    \
        float4 A = g4[0], Bv = g4[1];                                          \
        A.x += g4[2].x + g4[4].x + g4[6].x; A.y += g4[2].y + g4[4].y + g4[6].y;\
        A.z += g4[2].z + g4[4].z + g4[6].z; A.w += g4[2].w + g4[4].w + g4[6].w;\
        Bv.x += g4[3].x + g4[5].x + g4[7].x; Bv.y += g4[3].y + g4[5].y + g4[7].y;\
        Bv.z += g4[3].z + g4[5].z + g4[7].z; Bv.w += g4[3].w + g4[5].w + g4[7].w;\
        float l[8] = {A.x + bg[0], A.y + bg[1], A.z + bg[2], A.w + bg[3],      \
                      Bv.x + bg[4], Bv.y + bg[5], Bv.z + bg[6], Bv.w + bg[7]}; \
        float mx = fmaxf(fmaxf(fmaxf(l[0], l[1]), fmaxf(l[2], l[3])),          \
                         fmaxf(fmaxf(l[4], l[5]), fmaxf(l[6], l[7])));         \
        float e[8], s = 0.f;                                                   \
        _Pragma("unroll")                                                      \
        for (int m = 0; m < 8; ++m) { e[m] = __expf(l[m] - mx); s += e[m]; }   \
        float ks = e[0] * n0.x + e[1] * n0.y + e[2] * n0.z + e[3] * n0.w +     \
                   e[4] * n1.x + e[5] * n1.y + e[6] * n1.z + e[7] * n1.w;      \
        ks *= rcpf(s);                                                         \
        if (lane < NS) kst_sh[u] = (_Float16)ks;                               \
        if (lane == 31) {                                                      \
          out[(size_t)b * NT + t0 + tc - 1] = ks;                              \
          err_sh = ks - y_lds[tc - 1];                                         \
        }                                                                      \
      }                                                                        \
    } else { /* X: wait flag, batch issue at K==0, stage row tc */             \
      if ((K) == 0) {                                                          \
        const int needf = (min(tc4 + 8, CH - 1) >> 6) * NB + b;                \
        if (needf > readyf) { waitflag(&flags[needf]); readyf = needf; }       \
        const unsigned* xpg = (const unsigned*)xpre;                           \
        _Pragma("unroll")                                                      \
        for (int k = 0; k < 4; ++k) {                                          \
          const size_t rr = (size_t)(b * CH + tc4 + k) * 192;                  \
          xpq[3 * k + 0] = xpg[rr + lane];                                     \
          xpq[3 * k + 1] = xpg[rr + lane + 64];                                \
          xpq[3 * k + 2] = xpg[rr + lane + 128];                               \
        }                                                                      \
        const h8* xg0 = (const h8*)(xh16 + (size_t)(b * CH + min(tc4 + 1, CH - 1)) * NIN); \
        const h8* xg1 = (const h8*)(xh16 + (size_t)(b * CH + min(tc4 + 2, CH - 1)) * NIN); \
        const h8* xg2 = (const h8*)(xh16 + (size_t)(b * CH + min(tc4 + 3, CH - 1)) * NIN); \
        const h8* xg3 = (const h8*)(xh16 + (size_t)(b * CH + min(tc4 + 4, CH - 1)) * NIN); \
        _Pragma("unroll")                                                      \
        for (int i = 0; i < 4; ++i) {                                          \
          xr0[i] = xg0[i]; xr1[i] = xg1[i]; xr2[i] = xg2[i]; xr3[i] = xg3[i];  \
        }                                                                      \
      }                                                                        \
      unsigned* xps = (unsigned*)&xpre_sh[q][0];                               \
      xps[lane] = xpq[3 * (K) + 0];                                            \
      xps[lane + 64] = xpq[3 * (K) + 1];                                       \
      xps[lane + 128] = xpq[3 * (K) + 2];                                      \
    }                                                                          \
    __syncthreads();                                                           \
    /* ---------------- part B ---------------- */                             \
    if (wv >= 2) {                                                             \
      const float err = err_sh;                                                \
      const float xz = (float)xpre_sh[q][j] + err * wxe[0];                    \
      const float xr = (float)xpre_sh[q][j + 128] + err * wxe[1];              \
      const float xn = (float)xpre_sh[q][j + 256] + err * wxe[2];              \
      const float z = sigmoid_f(hz + xz);                                      \
      const float r = sigmoid_f(hr + xr);                                      \
      const float n = tanh_f(xn + r * hn);                                     \
      const float hnew = (1.f - z) * n + z * h_prev;                           \
      h_prev = hnew;                                                           \
      if (!half) h_sh[q][j] = (_Float16)hnew;                                  \
      float p[8];                                                              \
      _Pragma("unroll")                                                        \
      for (int m = 0; m < 8; ++m) p[m] = wave_reduce63(hnew * wg[m]);          \
      if (lane == 63) {                                                        \
        *(float4*)&gp_sh[q][wv - 2][0] = make_float4(p[0], p[1], p[2], p[3]);  \
        *(float4*)&gp_sh[q][wv - 2][4] = make_float4(p[4], p[5], p[6], p[7]);  \
      }                                                                        \
      const h8* kv8 = (const h8*)kst_sh;                                       \
      float s = xd_sh[qp][gl];                                                 \
      _Pragma("unroll")                                                        \
      for (int i = 0; i < 4; ++i) {                                            \
        const h8 kv = kv8[i];                                                  \
        s = fdot2(pick2<0>(kv), wrec[4 * i + 0], s);                           \
        s = fdot2(pick2<1>(kv), wrec[4 * i + 1], s);                           \
        s = fdot2(pick2<2>(kv), wrec[4 * i + 2], s);                           \
        s = fdot2(pick2<3>(kv), wrec[4 * i + 3], s);                           \
      }                                                                        \
      ns_sh[q][gl & 31][gl >> 5] = tanh_f(s);                                  \
    } else if (wv == 1) {                                                      \
      if (tc + 1 < CH) {                                                       \
        _Pragma("unroll")                                                      \
        for (int k = 0; k < 4; ++k) {                                          \
          float s = bs4[k];                                                    \
          _Pragma("unroll")                                                    \
          for (int i = 0; i < 4; ++i) {                                        \
            s = fdot2(pick2<0>(XRK[i]), wbig[k * 16 + 4 * i + 0], s);          \
            s = fdot2(pick2<1>(XRK[i]), wbig[k * 16 + 4 * i + 1], s);          \
            s = fdot2(pick2<2>(XRK[i]), wbig[k * 16 + 4 * i + 2], s);          \
            s = fdot2(pick2<3>(XRK[i]), wbig[k * 16 + 4 * i + 3], s);          \
          }                                                                    \
          xd_sh[q][lane + 64 * k] = s;                                         \
        }                                                                      \
      }                                                                        \
    }                                                                          \
    __syncthreads();                                                           \
  }

  for (int tc4 = 0; tc4 < CH; tc4 += 4) {
    STEPK(0, xr0)
    STEPK(1, xr1)
    STEPK(2, xr2)
    STEPK(3, xr3)
  }
#undef STEPK

  // ---- epilogue: softmax for the chunk's last step + state save ----
  if (wv == 0) {
    const int qf = (CH - 1) & 1;
    const int u = lane & 31;
    const float4* nsv = (const float4*)&ns_sh[qf][u][0];
    const float4 n0 = nsv[0], n1 = nsv[1];
    const float4* g4 = (const float4*)&gp_sh[qf][0][0];
    float4 A = g4[0], Bv = g4[1];
    A.x += g4[2].x + g4[4].x + g4[6].x; A.y += g4[2].y + g4[4].y + g4[6].y;
    A.z += g4[2].z + g4[4].z + g4[6].z; A.w += g4[2].w + g4[4].w + g4[6].w;
    Bv.x += g4[3].x + g4[5].x + g4[7].x; Bv.y += g4[3].y + g4[5].y + g4[7].y;
    Bv.z += g4[3].z + g4[5].z + g4[7].z; Bv.w += g4[3].w + g4[5].w + g4[7].w;
    float l[8] = {A.x + bg[0], A.y + bg[1], A.z + bg[2], A.w + bg[3],
                  Bv.x + bg[4], Bv.y + bg[5], Bv.z + bg[6], Bv.w + bg[7]};
    float mx = fmaxf(fmaxf(fmaxf(l[0], l[1]), fmaxf(l[2], l[3])),
                     fmaxf(fmaxf(l[4], l[5]), fmaxf(l[6], l[7])));
    float e[8], s = 0.f;
#pragma unroll
    for (int m = 0; m < 8; ++m) { e[m] = __expf(l[m] - mx); s += e[m]; }
    float ks = e[0] * n0.x + e[1] * n0.y + e[2] * n0.z + e[3] * n0.w +
               e[4] * n1.x + e[5] * n1.y + e[6] * n1.z + e[7] * n1.w;
    ks *= rcpf(s);
    if (lane < NS) st[NH + u] = ks;
    if (lane == 31) {
      out[(size_t)b * NT + t0 + CH - 1] = ks;
      st[NH + NS] = ks - y_lds[CH - 1];
    }
  }
  if (wv >= 2 && !half) st[j] = h_prev;
}

extern "C" void kernel_launch(void* const* d_in, const int* in_sizes, int n_in,
                              void* d_out, int out_size, void* d_ws, size_t ws_size,
                              hipStream_t stream) {
  const float* x = (const float*)d_in[0];
  const float* y = (const float*)d_in[1];
  const float* W_enc = (const float*)d_in[2];
  const float* b_enc = (const float*)d_in[3];
  const float* W_in = (const float*)d_in[4];
  const float* W_rec = (const float*)d_in[5];
  const float* b_s = (const float*)d_in[6];
  const float* W_x = (const float*)d_in[7];
  const float* W_h = (const float*)d_in[8];
  const float* b_x = (const float*)d_in[9];
  const float* b_h = (const float*)d_in[10];
  const float* W_gate = (const float*)d_in[11];
  const float* b_gate = (const float*)d_in[12];
  float* out = (float*)d_out;

  const size_t stateB = (size_t)NB * (NH + NS + 1) * sizeof(float);
  int CH = NT;
  while (CH > 64) {
    const size_t need = (size_t)NB * CH * NH3 * 2 + (size_t)NB * CH * NIN * 2 +
                        stateB + (size_t)(NB * CH / 64) * sizeof(int);
    if (need <= ws_size) break;
    CH >>= 1;
  }
  const int npre = NB * CH / 64;

  _Float16* xpre = (_Float16*)d_ws;
  _Float16* xh16 = (_Float16*)((char*)d_ws + (size_t)NB * CH * NH3 * 2);
  float* state = (float*)((char*)d_ws + (size_t)NB * CH * NH3 * 2 +
                          (size_t)NB * CH * NIN * 2);
  int* flags = (int*)((char*)state + stateB);

  for (int t0 = 0; t0 < NT; t0 += CH) {
    (void)hipMemsetAsync(flags, 0, (size_t)npre * sizeof(int), stream);
    fused<<<dim3(NB + npre), dim3(384), 0, stream>>>(
        x, y, W_enc, b_enc, W_in, W_rec, b_s, W_x, W_h, b_x, b_h, W_gate,
        b_gate, xpre, xh16, out, state, flags, t0, CH);
  }
}

// Round 19
// 2524.149 us; speedup vs baseline: 1.0213x; 1.0107x over previous
//
#include <hip/hip_runtime.h>

typedef _Float16 h2 __attribute__((ext_vector_type(2)));
typedef _Float16 h8 __attribute__((ext_vector_type(8)));

#define NB 128
#define NT 2048
#define NIN 32
#define NS 32
#define NM 8
#define NE 64
#define NH 128
#define NH3 384
#define RPW 16

__device__ __forceinline__ h2 mkh2(float a, float b) {
  h2 r; r[0] = (_Float16)a; r[1] = (_Float16)b; return r;
}

template <int I>
__device__ __forceinline__ h2 pick2(h8 v) {
  return __builtin_shufflevector(v, v, 2 * I, 2 * I + 1);
}

__device__ __forceinline__ float fdot2(h2 a, h2 b, float c) {
#if __has_builtin(__builtin_amdgcn_fdot2)
  return __builtin_amdgcn_fdot2(a, b, c, false);
#else
  return c + (float)a[0] * (float)b[0] + (float)a[1] * (float)b[1];
#endif
}

__device__ __forceinline__ float rcpf(float v) {
#if __has_builtin(__builtin_amdgcn_rcpf)
  return __builtin_amdgcn_rcpf(v);
#else
  return 1.0f / v;
#endif
}

__device__ __forceinline__ float sigmoid_f(float v) { return rcpf(1.0f + __expf(-v)); }
__device__ __forceinline__ float tanh_f(float v) { return 1.0f - 2.0f * rcpf(1.0f + __expf(2.0f * v)); }

__device__ __forceinline__ float f16bits_tof(unsigned short u) {
  _Float16 h;
  __builtin_memcpy(&h, &u, 2);
  return (float)h;
}

template <int CTRL>
__device__ __forceinline__ float dppadd(float v) {
  int t = __builtin_amdgcn_update_dpp(0, __float_as_int(v), CTRL, 0xF, 0xF, true);
  return v + __int_as_float(t);
}
__device__ __forceinline__ float wave_reduce63(float v) {
  v = dppadd<0x111>(v); v = dppadd<0x112>(v); v = dppadd<0x114>(v);
  v = dppadd<0x118>(v); v = dppadd<0x142>(v); v = dppadd<0x143>(v);
  return v;  // lane 63 holds the 64-lane sum
}
__device__ __forceinline__ float pairsum(float v) {
  int t = __builtin_amdgcn_update_dpp(0, __float_as_int(v), 0xB1, 0xF, 0xF, true);
  return v + __int_as_float(t);
}

__device__ __forceinline__ void lds_fence() {
  asm volatile("s_waitcnt lgkmcnt(0)" ::: "memory");
}

__device__ __forceinline__ void waitflag(int* f) {
  while (__hip_atomic_load(f, __ATOMIC_ACQUIRE, __HIP_MEMORY_SCOPE_AGENT) == 0)
    __builtin_amdgcn_s_sleep(2);
}

// ---------------------------------------------------------------------------
// Fused kernel (r16, best measured: 2525 us). Blocks [0, NB): the r8
// recurrent body. Blocks [NB, NB + NB*CH/64): the r8 pre body, chunk-major
// remap (pre block pb -> batch pb%NB, 64-row chunk pb/NB), ready flags with
// device-release / acquire ordering. Only the rnn X-wave waits on flags.
// ---------------------------------------------------------------------------
__global__ __launch_bounds__(384, 1) void fused(
    const float* __restrict__ gx, const float* __restrict__ gy,
    const float* __restrict__ W_enc, const float* __restrict__ b_enc,
    const float* __restrict__ W_in, const float* __restrict__ W_rec,
    const float* __restrict__ b_s, const float* __restrict__ W_x,
    const float* __restrict__ W_h, const float* __restrict__ b_x,
    const float* __restrict__ b_h, const float* __restrict__ W_gate,
    const float* __restrict__ b_gate, _Float16* __restrict__ xpre,
    _Float16* __restrict__ xh16, float* __restrict__ out,
    float* __restrict__ state, int* __restrict__ flags, int t0, int CH) {
  const int tid = threadIdx.x;

  // ---- shared (role-exclusive usage) ----
  __shared__ __align__(16) _Float16 x16[4][NIN];
  __shared__ __align__(16) _Float16 encA[4][RPW][NE];
  __shared__ __align__(16) _Float16 h_sh[2][NH];
  __shared__ __align__(16) _Float16 xpre_sh[2][NH3];
  __shared__ __align__(16) float ns_sh[2][NS][NM];
  __shared__ __align__(16) float xd_sh[2][2 * NH];
  __shared__ __align__(16) float gp_sh[2][4][NM];
  __shared__ __align__(16) _Float16 kst_sh[NS];
  __shared__ float err_sh;
  __shared__ float y_lds[NT];

  if (blockIdx.x >= NB) {
    // ==================== PRE ROLE (r8 pre2 body) ====================
    const int pb = (int)blockIdx.x - NB;
    const int bb = pb % NB;   // batch
    const int cc = pb / NB;   // 64-row chunk within this batch's CH rows
    if (tid < 256) {
      const int wv = tid >> 6, lane = tid & 63;
      h2 we[16];
#pragma unroll
      for (int i = 0; i < 16; ++i)
        we[i] = mkh2(W_enc[(2 * i) * NE + lane], W_enc[(2 * i + 1) * NE + lane]);
      const float be = b_enc[lane];
      const int tc0 = cc * 64 + wv * RPW;

      h2 wx3[96];
#pragma unroll 1
      for (int pass = 0; pass < 2; ++pass) {
#pragma unroll
        for (int kk = 0; kk < 3; ++kk) {
          const int j = lane + 64 * (3 * pass + kk);
#pragma unroll
          for (int i = 0; i < 32; ++i)
            wx3[kk * 32 + i] = mkh2(W_x[(size_t)(2 * i) * NH3 + j],
                                    W_x[(size_t)(2 * i + 1) * NH3 + j]);
        }
#pragma unroll 1
        for (int r = 0; r < RPW; ++r) {
          const int tc = tc0 + r;
          const size_t g = (size_t)bb * CH + tc;
          if (pass == 0) {
            const float* xr = gx + ((size_t)bb * NT + t0 + tc) * NIN;
            if (lane < NIN) x16[wv][lane] = (_Float16)xr[lane];
            lds_fence();
            if (lane < 16) {
              const unsigned v = *(const unsigned*)&x16[wv][2 * lane];
              ((unsigned*)xh16)[g * 16 + lane] = v;
            }
            const h8* xv8 = (const h8*)x16[wv];
            float a = be;
#pragma unroll
            for (int i = 0; i < 4; ++i) {
              const h8 xv = xv8[i];
              a = fdot2(pick2<0>(xv), we[4 * i + 0], a);
              a = fdot2(pick2<1>(xv), we[4 * i + 1], a);
              a = fdot2(pick2<2>(xv), we[4 * i + 2], a);
              a = fdot2(pick2<3>(xv), we[4 * i + 3], a);
            }
            encA[wv][r][lane] = (_Float16)tanh_f(a);
            lds_fence();
          }
          // FULL 64-element dot (r8 fix)
          const h8* ev8 = (const h8*)encA[wv][r];
          h8 ev[8];
#pragma unroll
          for (int i = 0; i < 8; ++i) ev[i] = ev8[i];
#pragma unroll
          for (int kk = 0; kk < 3; ++kk) {
            const int j = lane + 64 * (3 * pass + kk);
            float a = b_x[j], c = 0.f;
#pragma unroll
            for (int i = 0; i < 8; ++i) {
              a = fdot2(pick2<0>(ev[i]), wx3[kk * 32 + 4 * i + 0], a);
              c = fdot2(pick2<1>(ev[i]), wx3[kk * 32 + 4 * i + 1], c);
              a = fdot2(pick2<2>(ev[i]), wx3[kk * 32 + 4 * i + 2], a);
              c = fdot2(pick2<3>(ev[i]), wx3[kk * 32 + 4 * i + 3], c);
            }
            xpre[g * NH3 + j] = (_Float16)(a + c);
          }
        }
      }
    }
    // drain this thread's global stores, then join all waves
    asm volatile("s_waitcnt vmcnt(0)" ::: "memory");
    __syncthreads();
    if (tid == 0) {
      __threadfence();  // device-scope release for the xpre/xh16 stores
      __hip_atomic_store(&flags[pb], 1, __ATOMIC_RELEASE,
                         __HIP_MEMORY_SCOPE_AGENT);
    }
    return;
  }

  // ==================== RNN ROLE (r8 body + flag waits) ====================
  const int b = blockIdx.x;
  const int wv = tid >> 6;
  const int lane = tid & 63;

  float* st = state + b * (NH + NS + 1);

  h2 wbig[96];        // G: W_h 3 half-cols ; X: W_in 4 cols
  h2 wrec[16];        // G: W_rec col
  float wg[8];
  float bh[3], wxe[3];
  float bs4[4];
  float bg[8];
  float h_prev = 0.f;
  unsigned xpq[12];   // X: xpre rows tc4..tc4+3 (3 dwords each)
  h8 xr0[4], xr1[4], xr2[4], xr3[4];  // X: x rows
  int readyf = -1;

  const int gl = tid - 128;          // G: 0..255
  const int j = gl >> 1;             // G column
  const int half = gl & 1;

  // y preload (all waves) — one-time vmem, drained at the init barrier
  for (int i = tid; i < CH; i += 384) y_lds[i] = gy[(size_t)b * NT + t0 + i];

  if (wv >= 2) {
#pragma unroll
    for (int g = 0; g < 3; ++g) {
      const int jc = j + 128 * g;
#pragma unroll
      for (int i = 0; i < 32; ++i)
        wbig[g * 32 + i] = mkh2(W_h[(size_t)(64 * half + 2 * i) * NH3 + jc],
                                W_h[(size_t)(64 * half + 2 * i + 1) * NH3 + jc]);
      bh[g] = b_h[jc];
      wxe[g] = W_x[(size_t)NE * NH3 + jc];
    }
#pragma unroll
    for (int m = 0; m < 8; ++m) wg[m] = half ? 0.f : W_gate[j * NM + m];
    {
      const int m0 = gl >> 5, d0 = gl & 31;
#pragma unroll
      for (int i = 0; i < 16; ++i)
        wrec[i] = mkh2(W_rec[m0 * 1024 + (2 * i) * 32 + d0],
                       W_rec[m0 * 1024 + (2 * i + 1) * 32 + d0]);
    }
    h_prev = t0 ? st[j] : 0.f;
    if (!half) h_sh[1][j] = (_Float16)h_prev;
  } else if (wv == 1) {
#pragma unroll
    for (int k = 0; k < 4; ++k) {
      const int o = lane + 64 * k, m = o >> 5, d = o & 31;
#pragma unroll
      for (int i = 0; i < 16; ++i)
        wbig[k * 16 + i] = mkh2(W_in[m * 1024 + (2 * i) * 32 + d],
                                W_in[m * 1024 + (2 * i + 1) * 32 + d]);
      bs4[k] = b_s[o];
    }
    // wait for this batch's chunk 0 (rows 0..63) before reading xh16 rows 0..4
    waitflag(&flags[b]);
    readyf = b;
    // prologue: xd for step 0 from x row 0
    {
      const h8* x0 = (const h8*)(xh16 + (size_t)(b * CH) * NIN);
#pragma unroll
      for (int i = 0; i < 4; ++i) xr0[i] = x0[i];
#pragma unroll
      for (int k = 0; k < 4; ++k) {
        float s = bs4[k];
#pragma unroll
        for (int i = 0; i < 4; ++i) {
          s = fdot2(pick2<0>(xr0[i]), wbig[k * 16 + 4 * i + 0], s);
          s = fdot2(pick2<1>(xr0[i]), wbig[k * 16 + 4 * i + 1], s);
          s = fdot2(pick2<2>(xr0[i]), wbig[k * 16 + 4 * i + 2], s);
          s = fdot2(pick2<3>(xr0[i]), wbig[k * 16 + 4 * i + 3], s);
        }
        xd_sh[1][lane + 64 * k] = s;
      }
    }
  } else { // S
#pragma unroll
    for (int m = 0; m < 8; ++m) bg[m] = b_gate[m];
    if (lane < NS) kst_sh[lane] = t0 ? (_Float16)st[NH + lane] : (_Float16)0.f;
    if (lane == 0) err_sh = t0 ? st[NH + NS] : 0.f;
  }
  __syncthreads();

  float hz = 0.f, hr = 0.f, hn = 0.f;

#define STEPK(K, XRK)                                                          \
  {                                                                            \
    const int tc = tc4 + (K);                                                  \
    const int q = (K) & 1, qp = q ^ 1;                                         \
    /* ---------------- part A ---------------- */                             \
    if (wv >= 2) {                                                             \
      const h8* hv8 = (const h8*)&h_sh[qp][64 * half];                         \
      float a0 = 0.f, c0 = 0.f, a1 = 0.f, c1 = 0.f, a2 = 0.f, c2 = 0.f;        \
      _Pragma("unroll")                                                        \
      for (int i = 0; i < 8; ++i) {                                            \
        const h8 hv = hv8[i];                                                  \
        a0 = fdot2(pick2<0>(hv), wbig[4 * i + 0], a0);                         \
        c0 = fdot2(pick2<1>(hv), wbig[4 * i + 1], c0);                         \
        a0 = fdot2(pick2<2>(hv), wbig[4 * i + 2], a0);                         \
        c0 = fdot2(pick2<3>(hv), wbig[4 * i + 3], c0);                         \
        a1 = fdot2(pick2<0>(hv), wbig[32 + 4 * i + 0], a1);                    \
        c1 = fdot2(pick2<1>(hv), wbig[32 + 4 * i + 1], c1);                    \
        a1 = fdot2(pick2<2>(hv), wbig[32 + 4 * i + 2], a1);                    \
        c1 = fdot2(pick2<3>(hv), wbig[32 + 4 * i + 3], c1);                    \
        a2 = fdot2(pick2<0>(hv), wbig[64 + 4 * i + 0], a2);                    \
        c2 = fdot2(pick2<1>(hv), wbig[64 + 4 * i + 1], c2);                    \
        a2 = fdot2(pick2<2>(hv), wbig[64 + 4 * i + 2], a2);                    \
        c2 = fdot2(pick2<3>(hv), wbig[64 + 4 * i + 3], c2);                    \
      }                                                                        \
      hz = pairsum(a0 + c0) + bh[0];                                           \
      hr = pairsum(a1 + c1) + bh[1];                                           \
      hn = pairsum(a2 + c2) + bh[2];                                           \
    } else if (wv == 0) {                                                      \
      if (tc > 0) {                                                            \
        const int u = lane & 31;                                               \
        const float4* nsv = (const float4*)&ns_sh[qp][u][0];                   \
        const float4 n0 = nsv[0], n1 = nsv[1];                                 \
        const float4* g4 = (const float4*)&gp_sh[qp][0][0];                    \
        float4 A = g4[0], Bv = g4[1];                                          \
        A.x += g4[2].x + g4[4].x + g4[6].x; A.y += g4[2].y + g4[4].y + g4[6].y;\
        A.z += g4[2].z + g4[4].z + g4[6].z; A.w += g4[2].w + g4[4].w + g4[6].w;\
        Bv.x += g4[3].x + g4[5].x + g4[7].x; Bv.y += g4[3].y + g4[5].y + g4[7].y;\
        Bv.z += g4[3].z + g4[5].z + g4[7].z; Bv.w += g4[3].w + g4[5].w + g4[7].w;\
        float l[8] = {A.x + bg[0], A.y + bg[1], A.z + bg[2], A.w + bg[3],      \
                      Bv.x + bg[4], Bv.y + bg[5], Bv.z + bg[6], Bv.w + bg[7]}; \
        float mx = fmaxf(fmaxf(fmaxf(l[0], l[1]), fmaxf(l[2], l[3])),          \
                         fmaxf(fmaxf(l[4], l[5]), fmaxf(l[6], l[7])));         \
        float e[8], s = 0.f;                                                   \
        _Pragma("unroll")                                                      \
        for (int m = 0; m < 8; ++m) { e[m] = __expf(l[m] - mx); s += e[m]; }   \
        float ks = e[0] * n0.x + e[1] * n0.y + e[2] * n0.z + e[3] * n0.w +     \
                   e[4] * n1.x + e[5] * n1.y + e[6] * n1.z + e[7] * n1.w;      \
        ks *= rcpf(s);                                                         \
        if (lane < NS) kst_sh[u] = (_Float16)ks;                               \
        if (lane == 31) {                                                      \
          out[(size_t)b * NT + t0 + tc - 1] = ks;                              \
          err_sh = ks - y_lds[tc - 1];                                         \
        }                                                                      \
      }                                                                        \
    } else { /* X: wait flag, batch issue at K==0, stage row tc */             \
      if ((K) == 0) {                                                          \
        const int needf = (min(tc4 + 8, CH - 1) >> 6) * NB + b;                \
        if (needf > readyf) { waitflag(&flags[needf]); readyf = needf; }       \
        const unsigned* xpg = (const unsigned*)xpre;                           \
        _Pragma("unroll")                                                      \
        for (int k = 0; k < 4; ++k) {                                          \
          const size_t rr = (size_t)(b * CH + tc4 + k) * 192;                  \
          xpq[3 * k + 0] = xpg[rr + lane];                                     \
          xpq[3 * k + 1] = xpg[rr + lane + 64];                                \
          xpq[3 * k + 2] = xpg[rr + lane + 128];                               \
        }                                                                      \
        const h8* xg0 = (const h8*)(xh16 + (size_t)(b * CH + min(tc4 + 1, CH - 1)) * NIN); \
        const h8* xg1 = (const h8*)(xh16 + (size_t)(b * CH + min(tc4 + 2, CH - 1)) * NIN); \
        const h8* xg2 = (const h8*)(xh16 + (size_t)(b * CH + min(tc4 + 3, CH - 1)) * NIN); \
        const h8* xg3 = (const h8*)(xh16 + (size_t)(b * CH + min(tc4 + 4, CH - 1)) * NIN); \
        _Pragma("unroll")                                                      \
        for (int i = 0; i < 4; ++i) {                                          \
          xr0[i] = xg0[i]; xr1[i] = xg1[i]; xr2[i] = xg2[i]; xr3[i] = xg3[i];  \
        }                                                                      \
      }                                                                        \
      unsigned* xps = (unsigned*)&xpre_sh[q][0];                               \
      xps[lane] = xpq[3 * (K) + 0];                                            \
      xps[lane + 64] = xpq[3 * (K) + 1];                                       \
      xps[lane + 128] = xpq[3 * (K) + 2];                                      \
    }                                                                          \
    __syncthreads();                                                           \
    /* ---------------- part B ---------------- */                             \
    if (wv >= 2) {                                                             \
      const float err = err_sh;                                                \
      const float xz = (float)xpre_sh[q][j] + err * wxe[0];                    \
      const float xr = (float)xpre_sh[q][j + 128] + err * wxe[1];              \
      const float xn = (float)xpre_sh[q][j + 256] + err * wxe[2];              \
      const float z = sigmoid_f(hz + xz);                                      \
      const float r = sigmoid_f(hr + xr);                                      \
      const float n = tanh_f(xn + r * hn);                                     \
      const float hnew = (1.f - z) * n + z * h_prev;                           \
      h_prev = hnew;                                                           \
      if (!half) h_sh[q][j] = (_Float16)hnew;                                  \
      float p[8];                                                              \
      _Pragma("unroll")                                                        \
      for (int m = 0; m < 8; ++m) p[m] = wave_reduce63(hnew * wg[m]);          \
      if (lane == 63) {                                                        \
        *(float4*)&gp_sh[q][wv - 2][0] = make_float4(p[0], p[1], p[2], p[3]);  \
        *(float4*)&gp_sh[q][wv - 2][4] = make_float4(p[4], p[5], p[6], p[7]);  \
      }                                                                        \
      const h8* kv8 = (const h8*)kst_sh;                                       \
      float s = xd_sh[qp][gl];                                                 \
      _Pragma("unroll")                                                        \
      for (int i = 0; i < 4; ++i) {                                            \
        const h8 kv = kv8[i];                                                  \
        s = fdot2(pick2<0>(kv), wrec[4 * i + 0], s);                           \
        s = fdot2(pick2<1>(kv), wrec[4 * i + 1], s);                           \
        s = fdot2(pick2<2>(kv), wrec[4 * i + 2], s);                           \
        s = fdot2(pick2<3>(kv), wrec[4 * i + 3], s);                           \
      }                                                                        \
      ns_sh[q][gl & 31][gl >> 5] = tanh_f(s);                                  \
    } else if (wv == 1) {                                                      \
      if (tc + 1 < CH) {                                                       \
        _Pragma("unroll")                                                      \
        for (int k = 0; k < 4; ++k) {                                          \
          float s = bs4[k];                                                    \
          _Pragma("unroll")                                                    \
          for (int i = 0; i < 4; ++i) {                                        \
            s = fdot2(pick2<0>(XRK[i]), wbig[k * 16 + 4 * i + 0], s);          \
            s = fdot2(pick2<1>(XRK[i]), wbig[k * 16 + 4 * i + 1], s);          \
            s = fdot2(pick2<2>(XRK[i]), wbig[k * 16 + 4 * i + 2], s);          \
            s = fdot2(pick2<3>(XRK[i]), wbig[k * 16 + 4 * i + 3], s);          \
          }                                                                    \
          xd_sh[q][lane + 64 * k] = s;                                         \
        }                                                                      \
      }                                                                        \
    }                                                                          \
    __syncthreads();                                                           \
  }

  for (int tc4 = 0; tc4 < CH; tc4 += 4) {
    STEPK(0, xr0)
    STEPK(1, xr1)
    STEPK(2, xr2)
    STEPK(3, xr3)
  }
#undef STEPK

  // ---- epilogue: softmax for the chunk's last step + state save ----
  if (wv == 0) {
    const int qf = (CH - 1) & 1;
    const int u = lane & 31;
    const float4* nsv = (const float4*)&ns_sh[qf][u][0];
    const float4 n0 = nsv[0], n1 = nsv[1];
    const float4* g4 = (const float4*)&gp_sh[qf][0][0];
    float4 A = g4[0], Bv = g4[1];
    A.x += g4[2].x + g4[4].x + g4[6].x; A.y += g4[2].y + g4[4].y + g4[6].y;
    A.z += g4[2].z + g4[4].z + g4[6].z; A.w += g4[2].w + g4[4].w + g4[6].w;
    Bv.x += g4[3].x + g4[5].x + g4[7].x; Bv.y += g4[3].y + g4[5].y + g4[7].y;
    Bv.z += g4[3].z + g4[5].z + g4[7].z; Bv.w += g4[3].w + g4[5].w + g4[7].w;
    float l[8] = {A.x + bg[0], A.y + bg[1], A.z + bg[2], A.w + bg[3],
                  Bv.x + bg[4], Bv.y + bg[5], Bv.z + bg[6], Bv.w + bg[7]};
    float mx = fmaxf(fmaxf(fmaxf(l[0], l[1]), fmaxf(l[2], l[3])),
                     fmaxf(fmaxf(l[4], l[5]), fmaxf(l[6], l[7])));
    float e[8], s = 0.f;
#pragma unroll
    for (int m = 0; m < 8; ++m) { e[m] = __expf(l[m] - mx); s += e[m]; }
    float ks = e[0] * n0.x + e[1] * n0.y + e[2] * n0.z + e[3] * n0.w +
               e[4] * n1.x + e[5] * n1.y + e[6] * n1.z + e[7] * n1.w;
    ks *= rcpf(s);
    if (lane < NS) st[NH + u] = ks;
    if (lane == 31) {
      out[(size_t)b * NT + t0 + CH - 1] = ks;
      st[NH + NS] = ks - y_lds[CH - 1];
    }
  }
  if (wv >= 2 && !half) st[j] = h_prev;
}

extern "C" void kernel_launch(void* const* d_in, const int* in_sizes, int n_in,
                              void* d_out, int out_size, void* d_ws, size_t ws_size,
                              hipStream_t stream) {
  const float* x = (const float*)d_in[0];
  const float* y = (const float*)d_in[1];
  const float* W_enc = (const float*)d_in[2];
  const float* b_enc = (const float*)d_in[3];
  const float* W_in = (const float*)d_in[4];
  const float* W_rec = (const float*)d_in[5];
  const float* b_s = (const float*)d_in[6];
  const float* W_x = (const float*)d_in[7];
  const float* W_h = (const float*)d_in[8];
  const float* b_x = (const float*)d_in[9];
  const float* b_h = (const float*)d_in[10];
  const float* W_gate = (const float*)d_in[11];
  const float* b_gate = (const float*)d_in[12];
  float* out = (float*)d_out;

  const size_t stateB = (size_t)NB * (NH + NS + 1) * sizeof(float);
  int CH = NT;
  while (CH > 64) {
    const size_t need = (size_t)NB * CH * NH3 * 2 + (size_t)NB * CH * NIN * 2 +
                        stateB + (size_t)(NB * CH / 64) * sizeof(int);
    if (need <= ws_size) break;
    CH >>= 1;
  }
  const int npre = NB * CH / 64;

  _Float16* xpre = (_Float16*)d_ws;
  _Float16* xh16 = (_Float16*)((char*)d_ws + (size_t)NB * CH * NH3 * 2);
  float* state = (float*)((char*)d_ws + (size_t)NB * CH * NH3 * 2 +
                          (size_t)NB * CH * NIN * 2);
  int* flags = (int*)((char*)state + stateB);

  for (int t0 = 0; t0 < NT; t0 += CH) {
    (void)hipMemsetAsync(flags, 0, (size_t)npre * sizeof(int), stream);
    fused<<<dim3(NB + npre), dim3(384), 0, stream>>>(
        x, y, W_enc, b_enc, W_in, W_rec, b_s, W_x, W_h, b_x, b_h, W_gate,
        b_gate, xpre, xh16, out, state, flags, t0, CH);
  }
}